// Round 17
// baseline (53.369 us; speedup 1.0000x reference)
//
#include <hip/hip_runtime.h>

#define Bn 4
#define Dd 128
#define Hh 192
#define Ww 192

#define PLANE (Hh * Ww)           // 36864
#define VOL   (Dd * PLANE)
#define N2D   (Bn * PLANE)        // 147456
#define WARP_OFF ((size_t)N2D)
#define Y_OFF (WARP_OFF + (size_t)Bn * VOL)

// tile geometry: 16 x 8 x 32 voxels per block, 512 threads, 8 voxels/thread
#define DT 16
#define HT 8
#define WT 32
#define NDB (Dd / DT)     // 8
#define NHB (Hh / HT)     // 24
#define NWB (Ww / WT)     // 6
#define NBLK (Bn * NDB * NHB * NWB)   // 4608

// fixed-point scale for deterministic integer accumulation of x_2d
#define FPSCALE 1048576.0f            // 2^20
#define INV_FPD (1.0f / (FPSCALE * (float)Dd))

// LDS box: [SZ][SY][SXP]; one z-slice = 768 floats = 3 chunks of 64 lanes x 16B
#define SZ 25
#define SY 16
#define SXP 48
#define ZSTRIDE (SY * SXP)            // 768
#define LDSF (SZ * ZSTRIDE)           // 19200 floats = 76800 B

typedef float f2 __attribute__((ext_vector_type(2)));
typedef f2 __attribute__((aligned(4))) f2u;
__device__ __forceinline__ f2 load2(const float* p) { return *(const f2u*)p; }

__device__ __forceinline__ void gload_lds16(const float* g, float* l) {
    __builtin_amdgcn_global_load_lds(
        (const __attribute__((address_space(1))) void*)g,
        (__attribute__((address_space(3))) void*)l,
        16, 0, 0);
}

// ---------------- Kernel T: per-block table + zero the x_2d accumulator ---
// Box coords are UNCLAMPED source-space: lz/ly/lx4 may be negative or >= size.
// Out-of-volume box cells are zero-written at stage time (zero-pad semantics).
__global__ __launch_bounds__(256) void tbl_kernel(const float* __restrict__ rot0,
                                                  const float* __restrict__ rot1,
                                                  const float* __restrict__ rot2,
                                                  const float* __restrict__ tr1,
                                                  const float* __restrict__ tr2,
                                                  const float* __restrict__ cp,
                                                  float* __restrict__ tbl,
                                                  int* __restrict__ acc) {
    const int id = blockIdx.x * 256 + threadIdx.x;

    // fused: zero the accumulator (N2D ints over NBLK threads -> 32 each)
    {
        const int4 z4 = {0, 0, 0, 0};
        int base = id * 32;
        if (base < N2D) {
            #pragma unroll
            for (int i = 0; i < 8; ++i) *(int4*)(acc + base + 4 * i) = z4;
        }
    }

    if (id >= NBLK) return;
    const int wblk = id % NWB;
    const int t1   = id / NWB;
    const int hblk = t1 % NHB;
    const int t2   = t1 / NHB;
    const int dblk = t2 & (NDB - 1);
    const int b    = t2 >> 3;

    const float z = rot0[b], y = rot1[b], x = rot2[b];
    const float cz = cosf(z), sz = sinf(z);
    const float cy = cosf(y), sy = sinf(y);
    const float cx = cosf(x), sx = sinf(x);
    const float A0 = cz * cy;
    const float B0 = -sz * cx + cz * sy * sx;
    const float C0 = sz * sx + cz * sy * cx;
    const float A1 = sz * cy;
    const float B1 = cz * cx + sz * sy * sx;
    const float C1 = -cz * sx + sz * sy * cx;
    const float A2 = -sy;
    const float B2 = cy * sx;
    const float C2 = cy * cx;
    const float c0 = cp[b * 3 + 0], c1 = cp[b * 3 + 1], c2 = cp[b * 3 + 2];
    const float E0 = -(A0 * c0 + B0 * c1 + C0 * c2) + c0;
    const float E1 = -(A1 * c0 + B1 * c1 + C1 * c2) + tr1[b] * (float)Hh + c1;
    const float E2 = -(A2 * c0 + B2 * c1 + C2 * c2) + tr2[b] * (float)Ww + c2;

    const int d0 = dblk * DT, h0 = hblk * HT, w0 = wblk * WT;
    const float dlo = (float)d0, dhi = (float)(d0 + DT - 1);
    const float hlo = (float)h0, hhi = (float)(h0 + HT - 1);
    const float wlo = (float)w0, whi = (float)(w0 + WT - 1);

    const float loZ = E0 + fminf(A0 * dlo, A0 * dhi) + fminf(B0 * hlo, B0 * hhi) + fminf(C0 * wlo, C0 * whi);
    const float hiZ = E0 + fmaxf(A0 * dlo, A0 * dhi) + fmaxf(B0 * hlo, B0 * hhi) + fmaxf(C0 * wlo, C0 * whi);
    const float loY = E1 + fminf(A1 * dlo, A1 * dhi) + fminf(B1 * hlo, B1 * hhi) + fminf(C1 * wlo, C1 * whi);
    const float hiY = E1 + fmaxf(A1 * dlo, A1 * dhi) + fmaxf(B1 * hlo, B1 * hhi) + fmaxf(C1 * wlo, C1 * whi);
    const float loX = E2 + fminf(A2 * dlo, A2 * dhi) + fminf(B2 * hlo, B2 * hhi) + fminf(C2 * wlo, C2 * whi);
    const float hiX = E2 + fmaxf(A2 * dlo, A2 * dhi) + fmaxf(B2 * hlo, B2 * hhi) + fmaxf(C2 * wlo, C2 * whi);

    // UNCLAMPED bbox with +/-1 slack (negative & ~3 still floors to mult of 4)
    const int lz = (int)floorf(loZ) - 1;
    const int hz = (int)floorf(hiZ) + 2;
    const int ly = (int)floorf(loY) - 1;
    const int hy = (int)floorf(hiY) + 2;
    const int lx4 = ((int)floorf(loX) - 1) & ~3;
    const int hx = (int)floorf(hiX) + 2;

    const int hzrel = hz - lz;   // >= 3 always
    const bool fits = (hzrel <= SZ - 1) && (hy - ly <= SY - 1) && (hx - lx4 <= SXP - 2);

    // box-relative bases at (d0, h0, w0)
    const float bz = E0 + A0 * dlo + B0 * hlo + C0 * wlo - (float)lz;
    const float by = E1 + A1 * dlo + B1 * hlo + C1 * wlo - (float)ly;
    const float bx = E2 + A2 * dlo + B2 * hlo + C2 * wlo - (float)lx4;

    float* T = tbl + (size_t)id * 16;
    T[0] = A0; T[1] = B0; T[2]  = C0; T[3]  = bz;
    T[4] = A1; T[5] = B1; T[6]  = C1; T[7]  = by;
    T[8] = A2; T[9] = B2; T[10] = C2; T[11] = bx;
    int* TI = (int*)T;
    TI[12] = lz; TI[13] = ly; TI[14] = lx4;
    // bits: fits(0) b(2-3) dblk(4-6) hblk(7-11) wblk(12-14) hzrel(15-21)
    TI[15] = (fits ? 1 : 0) |
             (b << 2) | (dblk << 4) | (hblk << 7) | (wblk << 12) | (min(hzrel, 127) << 15);
}

// ---------------- Kernel B: LDS-tiled warp (fused zero-write staging) -----
// x_2d accumulation: one deterministic integer atomicAdd per thread.
__global__ __launch_bounds__(512) void warp_tiled(const float* __restrict__ x,
                                                  const float* __restrict__ tbl,
                                                  float* __restrict__ out,
                                                  int* __restrict__ acc) {
    __shared__ __align__(16) float box[LDSF];

    // XCD-aware swizzle (4608 % 8 == 0 -> bijective)
    const int g  = blockIdx.x;
    const int wl = (g & 7) * (NBLK / 8) + (g >> 3);

    const float4* T4 = (const float4*)(tbl + (size_t)wl * 16);
    const float4 r0 = T4[0], r1 = T4[1], r2 = T4[2];
    const int4   r3 = ((const int4*)T4)[3];
    const int lz = r3.x, ly = r3.y, lx4 = r3.z, fl = r3.w;
    const bool fits = fl & 1;
    const int b     = (fl >> 2) & 3;
    const int dblk  = (fl >> 4) & 7;
    const int hblk  = (fl >> 7) & 31;
    const int wblk  = (fl >> 12) & 7;
    const int hzrel = (fl >> 15) & 127;
    const int d0 = dblk * DT, h0 = hblk * HT, w0 = wblk * WT;

    const float A0 = r0.x, B0 = r0.y, C0 = r0.z, bz = r0.w;
    const float A1 = r1.x, B1 = r1.y, C1 = r1.z, by = r1.w;
    const float A2 = r2.x, B2 = r2.y, C2 = r2.z, bx = r2.w;

    const int t = threadIdx.x;
    const int w_in = t & 31;
    const int h_in = (t >> 5) & 7;     // 0..7
    const int dq   = t >> 8;           // 0/1 -> d half (8 voxels each)
    const int lane = t & 63;
    const int wid  = t >> 6;           // 0..7

    const float fh = (float)h_in, fw = (float)w_in, fdq = (float)(dq * 8);
    // box-relative per-thread bases at j=0 (includes dq offset)
    const float fz0 = bz + B0 * fh + C0 * fw + A0 * fdq;
    const float fy0 = by + B1 * fh + C1 * fw + A1 * fdq;
    const float fx0 = bx + B2 * fh + C2 * fw + A2 * fdq;

    const float* __restrict__ V = x + (size_t)b * VOL;
    float* __restrict__ obase = out + WARP_OFF + (size_t)b * VOL +
                                (size_t)(d0 + dq * 8) * PLANE +
                                (size_t)(h0 + h_in) * Ww + (w0 + w_in);

    float sum = 0.0f;

    if (fits) {
        // per-lane staging map: cell idx -> (row, 4-col) within a z-slice
        const int r0i = lane / 12,             c0i = (lane - r0i * 12) * 4;
        const int i1  = 64 + lane;  const int r1i = i1 / 12, c1i = (i1 - r1i * 12) * 4;
        const int i2  = 128 + lane; const int r2i = i2 / 12, c2i = (i2 - r2i * 12) * 4;
        const int yy0 = ly + r0i, xx0 = lx4 + c0i;
        const int yy1 = ly + r1i, xx1 = lx4 + c1i;
        const int yy2 = ly + r2i, xx2 = lx4 + c2i;
        const bool ok0 = ((unsigned)yy0 < (unsigned)Hh) && ((unsigned)xx0 <= (unsigned)(Ww - 4));
        const bool ok1 = ((unsigned)yy1 < (unsigned)Hh) && ((unsigned)xx1 <= (unsigned)(Ww - 4));
        const bool ok2 = ((unsigned)yy2 < (unsigned)Hh) && ((unsigned)xx2 <= (unsigned)(Ww - 4));
        const int off0 = yy0 * Ww + xx0;
        const int off1 = yy1 * Ww + xx1;
        const int off2 = yy2 * Ww + xx2;

        // fused staging: DMA in-volume cells, ds_write zeros for the rest.
        // Covers exactly slices [0, hzrel] x 16 rows x 48 cols = everything the
        // sampler can read (izr+1 <= hzrel-1, iyr+1 <= 15, ixr+1 <= 47).
        const float4 z4 = {0.0f, 0.0f, 0.0f, 0.0f};
        for (int zrel = wid; zrel <= hzrel; zrel += 8) {
            const int zz = lz + zrel;                 // wave-uniform
            float* Lz = box + zrel * ZSTRIDE;
            if ((unsigned)zz < (unsigned)Dd) {
                const float* Vz = V + (size_t)zz * PLANE;
                if (ok0) gload_lds16(Vz + off0, Lz);
                else     *((float4*)Lz + lane) = z4;
                if (ok1) gload_lds16(Vz + off1, Lz + 256);
                else     *((float4*)(Lz + 256) + lane) = z4;
                if (ok2) gload_lds16(Vz + off2, Lz + 512);
                else     *((float4*)(Lz + 512) + lane) = z4;
            } else {
                *((float4*)Lz + lane) = z4;
                *((float4*)(Lz + 256) + lane) = z4;
                *((float4*)(Lz + 512) + lane) = z4;
            }
        }

        // T14: precompute all addresses/weights BEFORE the barrier
        int   basev[8];
        float txv[8], tyv[8], tzv[8];
        #pragma unroll
        for (int j = 0; j < 8; ++j) {
            const float fd = (float)j;
            const float gz = fmaf(A0, fd, fz0);
            const float gy = fmaf(A1, fd, fy0);
            const float gx = fmaf(A2, fd, fx0);
            const float fz = floorf(gz), fy = floorf(gy), fx = floorf(gx);
            tzv[j] = gz - fz; tyv[j] = gy - fy; txv[j] = gx - fx;
            basev[j] = (int)fz * ZSTRIDE + (int)fy * SXP + (int)fx;
        }
        __syncthreads();   // DMA/zero drain (precompute overlapped it)

        // unified no-mask sample path (zero cells give exact zero-padding)
        #pragma unroll
        for (int j = 0; j < 8; ++j) {
            const int base = basev[j];
            const f2 qa = load2(&box[base]);
            const f2 qb = load2(&box[base + SXP]);
            const f2 qc = load2(&box[base + ZSTRIDE]);
            const f2 qd = load2(&box[base + ZSTRIDE + SXP]);

            const float tx = txv[j], ty = tyv[j], tz = tzv[j];
            const float wx0 = 1.0f - tx, wy0 = 1.0f - ty, wz0 = 1.0f - tz;
            const float v00 = fmaf(wx0, qa.x, tx * qa.y);
            const float v01 = fmaf(wx0, qb.x, tx * qb.y);
            const float v10 = fmaf(wx0, qc.x, tx * qc.y);
            const float v11 = fmaf(wx0, qd.x, tx * qd.y);
            const float vz0 = fmaf(wy0, v00, ty * v01);
            const float vz1 = fmaf(wy0, v10, ty * v11);
            const float val = fmaf(wz0, vz0, tz * vz1);

            __builtin_nontemporal_store(val, obase + (size_t)j * PLANE);
            sum += val;
        }
    } else {
        // global-gather fallback (extreme rotations only)
        const float fz0a = fz0 + (float)lz;
        const float fy0a = fy0 + (float)ly;
        const float fx0a = fx0 + (float)lx4;
        #pragma unroll 4
        for (int j = 0; j < 8; ++j) {
            const float fd = (float)j;
            const float gz = fmaf(A0, fd, fz0a);
            const float gy = fmaf(A1, fd, fy0a);
            const float gx = fmaf(A2, fd, fx0a);

            const float fz = floorf(gz), fy = floorf(gy), fx = floorf(gx);
            const float tz = gz - fz, ty = gy - fy, tx = gx - fx;
            const int iz = (int)fz, iy = (int)fy, ix = (int)fx;

            const float wz0 = ((unsigned)iz       < (unsigned)Dd) ? (1.0f - tz) : 0.0f;
            const float wz1 = ((unsigned)(iz + 1) < (unsigned)Dd) ? tz : 0.0f;
            const float wy0 = ((unsigned)iy       < (unsigned)Hh) ? (1.0f - ty) : 0.0f;
            const float wy1 = ((unsigned)(iy + 1) < (unsigned)Hh) ? ty : 0.0f;
            const float wx0 = ((unsigned)ix       < (unsigned)Ww) ? (1.0f - tx) : 0.0f;
            const float wx1 = ((unsigned)(ix + 1) < (unsigned)Ww) ? tx : 0.0f;

            const bool right  = (ix >= Ww - 1);
            const bool leftok = (ix >= 0);
            const float WL = (right ? 0.0f : wx0) + (leftok ? 0.0f : wx1);
            const float WH = (right ? wx0 : 0.0f) + (leftok ? wx1 : 0.0f);

            const int iz0c = min(max(iz, 0), Dd - 1);
            const int iz1c = min(max(iz + 1, 0), Dd - 1);
            const int iy0c = min(max(iy, 0), Hh - 1);
            const int iy1c = min(max(iy + 1, 0), Hh - 1);
            const int ixl  = min(max(ix, 0), Ww - 2);

            const f2 q00 = load2(V + (size_t)iz0c * PLANE + iy0c * Ww + ixl);
            const f2 q01 = load2(V + (size_t)iz0c * PLANE + iy1c * Ww + ixl);
            const f2 q10 = load2(V + (size_t)iz1c * PLANE + iy0c * Ww + ixl);
            const f2 q11 = load2(V + (size_t)iz1c * PLANE + iy1c * Ww + ixl);

            const float v00 = fmaf(WL, q00.x, WH * q00.y);
            const float v01 = fmaf(WL, q01.x, WH * q01.y);
            const float v10 = fmaf(WL, q10.x, WH * q10.y);
            const float v11 = fmaf(WL, q11.x, WH * q11.y);

            const float vz0 = fmaf(wy0, v00, wy1 * v01);
            const float vz1 = fmaf(wy0, v10, wy1 * v11);
            const float val = fmaf(wz0, vz0, wz1 * vz1);

            __builtin_nontemporal_store(val, obase + (size_t)j * PLANE);
            sum += val;
        }
    }

    // deterministic fixed-point accumulation of x_2d (int add is associative)
    const int pix = (b * Hh + (h0 + h_in)) * Ww + (w0 + w_in);
    atomicAdd(acc + pix, (int)rintf(sum * FPSCALE));
}

// ---------------- Kernel C: convert acc -> x_2d, copy y (float4) ----------
__global__ __launch_bounds__(256) void reduce_kernel(const int* __restrict__ acc,
                                                     const float* __restrict__ yin,
                                                     float* __restrict__ out) {
    const int q = blockIdx.x * 256 + threadIdx.x;   // quad index
    if (q >= N2D / 4) return;
    const int idx = q * 4;
    const int4 a = *(const int4*)(acc + idx);
    float4 s;
    s.x = (float)a.x * INV_FPD;
    s.y = (float)a.y * INV_FPD;
    s.z = (float)a.z * INV_FPD;
    s.w = (float)a.w * INV_FPD;
    *(float4*)(out + idx) = s;
    *(float4*)(out + Y_OFF + idx) = *(const float4*)(yin + idx);
}

extern "C" void kernel_launch(void* const* d_in, const int* in_sizes, int n_in,
                              void* d_out, int out_size, void* d_ws, size_t ws_size,
                              hipStream_t stream) {
    const float* x    = (const float*)d_in[0];
    const float* yin  = (const float*)d_in[1];
    const float* rot0 = (const float*)d_in[2];
    const float* rot1 = (const float*)d_in[3];
    const float* rot2 = (const float*)d_in[4];
    const float* tr1  = (const float*)d_in[5];
    const float* tr2  = (const float*)d_in[6];
    const float* cp   = (const float*)d_in[7];

    float* tbl = (float*)d_ws;                       // NBLK*16 floats = 295 KB
    int*   acc = (int*)(tbl + (size_t)NBLK * 16);    // N2D ints = 590 KB
    (void)ws_size;                                   // ws is amply sized

    tbl_kernel<<<(NBLK + 255) / 256, 256, 0, stream>>>(rot0, rot1, rot2, tr1, tr2, cp, tbl, acc);
    warp_tiled<<<NBLK, 512, 0, stream>>>(x, tbl, (float*)d_out, acc);
    reduce_kernel<<<(N2D / 4 + 255) / 256, 256, 0, stream>>>(acc, yin, (float*)d_out);
}

// Round 18
// 49.352 us; speedup vs baseline: 1.0814x; 1.0814x over previous
//
#include <hip/hip_runtime.h>

#define Bn 4
#define Dd 128
#define Hh 192
#define Ww 192

#define PLANE (Hh * Ww)           // 36864
#define VOL   (Dd * PLANE)
#define N2D   (Bn * PLANE)        // 147456
#define WARP_OFF ((size_t)N2D)
#define Y_OFF (WARP_OFF + (size_t)Bn * VOL)

// tile geometry: 16 x 8 x 32 voxels per block, 512 threads, 8 voxels/thread
#define DT 16
#define HT 8
#define WT 32
#define NDB (Dd / DT)     // 8
#define NHB (Hh / HT)     // 24
#define NWB (Ww / WT)     // 6
#define NBLK (Bn * NDB * NHB * NWB)   // 4608

// fixed-point scale for deterministic integer accumulation of x_2d
#define FPSCALE 1048576.0f            // 2^20
#define INV_FPD (1.0f / (FPSCALE * (float)Dd))

// LDS box: [SZ][SY][SXP]; one z-slice = 768 floats = 3 chunks of 64 lanes x 16B
#define SZ 25
#define SY 16
#define SXP 48
#define ZSTRIDE (SY * SXP)            // 768
#define LDSF (SZ * ZSTRIDE)           // 19200 floats = 76800 B

typedef float f2 __attribute__((ext_vector_type(2)));
typedef f2 __attribute__((aligned(4))) f2u;
__device__ __forceinline__ f2 load2(const float* p) { return *(const f2u*)p; }

__device__ __forceinline__ void gload_lds16(const float* g, float* l) {
    __builtin_amdgcn_global_load_lds(
        (const __attribute__((address_space(1))) void*)g,
        (__attribute__((address_space(3))) void*)l,
        16, 0, 0);
}

// ---------------- Kernel T: per-block table + zero the x_2d accumulator ---
// Box coords are UNCLAMPED source-space: lz/ly/lx4 may be negative or >= size.
// Out-of-volume box cells are zero-filled at stage time (zero-pad semantics).
__global__ __launch_bounds__(256) void tbl_kernel(const float* __restrict__ rot0,
                                                  const float* __restrict__ rot1,
                                                  const float* __restrict__ rot2,
                                                  const float* __restrict__ tr1,
                                                  const float* __restrict__ tr2,
                                                  const float* __restrict__ cp,
                                                  float* __restrict__ tbl,
                                                  int* __restrict__ acc) {
    const int id = blockIdx.x * 256 + threadIdx.x;

    // fused: zero the accumulator (N2D ints over NBLK threads -> 32 each)
    {
        const int4 z4 = {0, 0, 0, 0};
        int base = id * 32;
        if (base < N2D) {
            #pragma unroll
            for (int i = 0; i < 8; ++i) *(int4*)(acc + base + 4 * i) = z4;
        }
    }

    if (id >= NBLK) return;
    const int wblk = id % NWB;
    const int t1   = id / NWB;
    const int hblk = t1 % NHB;
    const int t2   = t1 / NHB;
    const int dblk = t2 & (NDB - 1);
    const int b    = t2 >> 3;

    const float z = rot0[b], y = rot1[b], x = rot2[b];
    const float cz = cosf(z), sz = sinf(z);
    const float cy = cosf(y), sy = sinf(y);
    const float cx = cosf(x), sx = sinf(x);
    const float A0 = cz * cy;
    const float B0 = -sz * cx + cz * sy * sx;
    const float C0 = sz * sx + cz * sy * cx;
    const float A1 = sz * cy;
    const float B1 = cz * cx + sz * sy * sx;
    const float C1 = -cz * sx + sz * sy * cx;
    const float A2 = -sy;
    const float B2 = cy * sx;
    const float C2 = cy * cx;
    const float c0 = cp[b * 3 + 0], c1 = cp[b * 3 + 1], c2 = cp[b * 3 + 2];
    const float E0 = -(A0 * c0 + B0 * c1 + C0 * c2) + c0;
    const float E1 = -(A1 * c0 + B1 * c1 + C1 * c2) + tr1[b] * (float)Hh + c1;
    const float E2 = -(A2 * c0 + B2 * c1 + C2 * c2) + tr2[b] * (float)Ww + c2;

    const int d0 = dblk * DT, h0 = hblk * HT, w0 = wblk * WT;
    const float dlo = (float)d0, dhi = (float)(d0 + DT - 1);
    const float hlo = (float)h0, hhi = (float)(h0 + HT - 1);
    const float wlo = (float)w0, whi = (float)(w0 + WT - 1);

    const float loZ = E0 + fminf(A0 * dlo, A0 * dhi) + fminf(B0 * hlo, B0 * hhi) + fminf(C0 * wlo, C0 * whi);
    const float hiZ = E0 + fmaxf(A0 * dlo, A0 * dhi) + fmaxf(B0 * hlo, B0 * hhi) + fmaxf(C0 * wlo, C0 * whi);
    const float loY = E1 + fminf(A1 * dlo, A1 * dhi) + fminf(B1 * hlo, B1 * hhi) + fminf(C1 * wlo, C1 * whi);
    const float hiY = E1 + fmaxf(A1 * dlo, A1 * dhi) + fmaxf(B1 * hlo, B1 * hhi) + fmaxf(C1 * wlo, C1 * whi);
    const float loX = E2 + fminf(A2 * dlo, A2 * dhi) + fminf(B2 * hlo, B2 * hhi) + fminf(C2 * wlo, C2 * whi);
    const float hiX = E2 + fmaxf(A2 * dlo, A2 * dhi) + fmaxf(B2 * hlo, B2 * hhi) + fmaxf(C2 * wlo, C2 * whi);

    // UNCLAMPED bbox with +/-1 slack (negative & ~3 still floors to mult of 4)
    const int lz = (int)floorf(loZ) - 1;
    const int hz = (int)floorf(hiZ) + 2;
    const int ly = (int)floorf(loY) - 1;
    const int hy = (int)floorf(hiY) + 2;
    const int lx4 = ((int)floorf(loX) - 1) & ~3;
    const int hx = (int)floorf(hiX) + 2;

    const int hzrel = hz - lz;   // >= 3 always
    const bool fits = (hzrel <= SZ - 1) && (hy - ly <= SY - 1) && (hx - lx4 <= SXP - 2);
    const bool interior = (loZ >= 0.01f) && (hiZ < (float)(Dd - 1) - 0.01f) &&
                          (loY >= 0.01f) && (hiY < (float)(Hh - 1) - 0.01f) &&
                          (loX >= 0.01f) && (hiX < (float)(Ww - 1) - 0.01f);

    // box-relative bases at (d0, h0, w0)
    const float bz = E0 + A0 * dlo + B0 * hlo + C0 * wlo - (float)lz;
    const float by = E1 + A1 * dlo + B1 * hlo + C1 * wlo - (float)ly;
    const float bx = E2 + A2 * dlo + B2 * hlo + C2 * wlo - (float)lx4;

    float* T = tbl + (size_t)id * 16;
    T[0] = A0; T[1] = B0; T[2]  = C0; T[3]  = bz;
    T[4] = A1; T[5] = B1; T[6]  = C1; T[7]  = by;
    T[8] = A2; T[9] = B2; T[10] = C2; T[11] = bx;
    int* TI = (int*)T;
    TI[12] = lz; TI[13] = ly; TI[14] = lx4;
    // bits: fits(0) interior(1) b(2-3) dblk(4-6) hblk(7-11) wblk(12-14) hzrel(15-21)
    TI[15] = (fits ? 1 : 0) | (interior ? 2 : 0) |
             (b << 2) | (dblk << 4) | (hblk << 7) | (wblk << 12) | (min(hzrel, 127) << 15);
}

// ---------------- Kernel B: LDS-tiled warp (zero-pad staging) -------------
// x_2d accumulation: one deterministic integer atomicAdd per thread.
__global__ __launch_bounds__(512) void warp_tiled(const float* __restrict__ x,
                                                  const float* __restrict__ tbl,
                                                  float* __restrict__ out,
                                                  int* __restrict__ acc) {
    __shared__ __align__(16) float box[LDSF];

    // XCD-aware swizzle (4608 % 8 == 0 -> bijective)
    const int g  = blockIdx.x;
    const int wl = (g & 7) * (NBLK / 8) + (g >> 3);

    const float4* T4 = (const float4*)(tbl + (size_t)wl * 16);
    const float4 r0 = T4[0], r1 = T4[1], r2 = T4[2];
    const int4   r3 = ((const int4*)T4)[3];
    const int lz = r3.x, ly = r3.y, lx4 = r3.z, fl = r3.w;
    const bool fits = fl & 1, interior = fl & 2;
    const int b     = (fl >> 2) & 3;
    const int dblk  = (fl >> 4) & 7;
    const int hblk  = (fl >> 7) & 31;
    const int wblk  = (fl >> 12) & 7;
    const int hzrel = (fl >> 15) & 127;
    const int d0 = dblk * DT, h0 = hblk * HT, w0 = wblk * WT;

    const float A0 = r0.x, B0 = r0.y, C0 = r0.z, bz = r0.w;
    const float A1 = r1.x, B1 = r1.y, C1 = r1.z, by = r1.w;
    const float A2 = r2.x, B2 = r2.y, C2 = r2.z, bx = r2.w;

    const int t = threadIdx.x;
    const int w_in = t & 31;
    const int h_in = (t >> 5) & 7;     // 0..7
    const int dq   = t >> 8;           // 0/1 -> d half (8 voxels each)
    const int lane = t & 63;
    const int wid  = t >> 6;           // 0..7

    const float fh = (float)h_in, fw = (float)w_in, fdq = (float)(dq * 8);
    // box-relative per-thread bases at j=0 (includes dq offset)
    const float fz0 = bz + B0 * fh + C0 * fw + A0 * fdq;
    const float fy0 = by + B1 * fh + C1 * fw + A1 * fdq;
    const float fx0 = bx + B2 * fh + C2 * fw + A2 * fdq;

    const float* __restrict__ V = x + (size_t)b * VOL;
    float* __restrict__ obase = out + WARP_OFF + (size_t)b * VOL +
                                (size_t)(d0 + dq * 8) * PLANE +
                                (size_t)(h0 + h_in) * Ww + (w0 + w_in);

    float sum = 0.0f;

    if (fits) {
        // per-lane staging map: cell idx -> (row, 4-col) within a z-slice
        const int r0i = lane / 12,             c0i = (lane - r0i * 12) * 4;
        const int i1  = 64 + lane;  const int r1i = i1 / 12, c1i = (i1 - r1i * 12) * 4;
        const int i2  = 128 + lane; const int r2i = i2 / 12, c2i = (i2 - r2i * 12) * 4;
        const int yy0 = ly + r0i, xx0 = lx4 + c0i;
        const int yy1 = ly + r1i, xx1 = lx4 + c1i;
        const int yy2 = ly + r2i, xx2 = lx4 + c2i;
        const bool ok0 = ((unsigned)yy0 < (unsigned)Hh) && ((unsigned)xx0 <= (unsigned)(Ww - 4));
        const bool ok1 = ((unsigned)yy1 < (unsigned)Hh) && ((unsigned)xx1 <= (unsigned)(Ww - 4));
        const bool ok2 = ((unsigned)yy2 < (unsigned)Hh) && ((unsigned)xx2 <= (unsigned)(Ww - 4));
        const int off0 = yy0 * Ww + xx0;
        const int off1 = yy1 * Ww + xx1;
        const int off2 = yy2 * Ww + xx2;

        if (!interior) {
            // zero-fill: unstaged (out-of-volume) cells must read as 0
            const float4 z4 = {0.0f, 0.0f, 0.0f, 0.0f};
            for (int i = 4 * t; i < LDSF; i += 4 * 512) *(float4*)&box[i] = z4;
            __syncthreads();
        }

        // predicated DMA staging: only in-volume cells load; others keep 0
        for (int zrel = wid; zrel <= hzrel; zrel += 8) {
            const int zz = lz + zrel;                 // wave-uniform
            if ((unsigned)zz < (unsigned)Dd) {
                const float* Vz = V + (size_t)zz * PLANE;
                float* Lz = box + zrel * ZSTRIDE;
                if (ok0) gload_lds16(Vz + off0, Lz);
                if (ok1) gload_lds16(Vz + off1, Lz + 256);
                if (ok2) gload_lds16(Vz + off2, Lz + 512);
            }
        }

        // T14: precompute all addresses/weights BEFORE the barrier
        int   basev[8];
        float txv[8], tyv[8], tzv[8];
        #pragma unroll
        for (int j = 0; j < 8; ++j) {
            const float fd = (float)j;
            const float gz = fmaf(A0, fd, fz0);
            const float gy = fmaf(A1, fd, fy0);
            const float gx = fmaf(A2, fd, fx0);
            const float fz = floorf(gz), fy = floorf(gy), fx = floorf(gx);
            tzv[j] = gz - fz; tyv[j] = gy - fy; txv[j] = gx - fx;
            basev[j] = (int)fz * ZSTRIDE + (int)fy * SXP + (int)fx;
        }
        __syncthreads();   // DMA drain overlapped the precompute above

        // unified no-mask sample path (zero cells give exact zero-padding)
        #pragma unroll
        for (int j = 0; j < 8; ++j) {
            const int base = basev[j];
            const f2 qa = load2(&box[base]);
            const f2 qb = load2(&box[base + SXP]);
            const f2 qc = load2(&box[base + ZSTRIDE]);
            const f2 qd = load2(&box[base + ZSTRIDE + SXP]);

            const float tx = txv[j], ty = tyv[j], tz = tzv[j];
            const float wx0 = 1.0f - tx, wy0 = 1.0f - ty, wz0 = 1.0f - tz;
            const float v00 = fmaf(wx0, qa.x, tx * qa.y);
            const float v01 = fmaf(wx0, qb.x, tx * qb.y);
            const float v10 = fmaf(wx0, qc.x, tx * qc.y);
            const float v11 = fmaf(wx0, qd.x, tx * qd.y);
            const float vz0 = fmaf(wy0, v00, ty * v01);
            const float vz1 = fmaf(wy0, v10, ty * v11);
            const float val = fmaf(wz0, vz0, tz * vz1);

            __builtin_nontemporal_store(val, obase + (size_t)j * PLANE);
            sum += val;
        }
    } else {
        // global-gather fallback (extreme rotations only)
        const float fz0a = fz0 + (float)lz;
        const float fy0a = fy0 + (float)ly;
        const float fx0a = fx0 + (float)lx4;
        #pragma unroll 4
        for (int j = 0; j < 8; ++j) {
            const float fd = (float)j;
            const float gz = fmaf(A0, fd, fz0a);
            const float gy = fmaf(A1, fd, fy0a);
            const float gx = fmaf(A2, fd, fx0a);

            const float fz = floorf(gz), fy = floorf(gy), fx = floorf(gx);
            const float tz = gz - fz, ty = gy - fy, tx = gx - fx;
            const int iz = (int)fz, iy = (int)fy, ix = (int)fx;

            const float wz0 = ((unsigned)iz       < (unsigned)Dd) ? (1.0f - tz) : 0.0f;
            const float wz1 = ((unsigned)(iz + 1) < (unsigned)Dd) ? tz : 0.0f;
            const float wy0 = ((unsigned)iy       < (unsigned)Hh) ? (1.0f - ty) : 0.0f;
            const float wy1 = ((unsigned)(iy + 1) < (unsigned)Hh) ? ty : 0.0f;
            const float wx0 = ((unsigned)ix       < (unsigned)Ww) ? (1.0f - tx) : 0.0f;
            const float wx1 = ((unsigned)(ix + 1) < (unsigned)Ww) ? tx : 0.0f;

            const bool right  = (ix >= Ww - 1);
            const bool leftok = (ix >= 0);
            const float WL = (right ? 0.0f : wx0) + (leftok ? 0.0f : wx1);
            const float WH = (right ? wx0 : 0.0f) + (leftok ? wx1 : 0.0f);

            const int iz0c = min(max(iz, 0), Dd - 1);
            const int iz1c = min(max(iz + 1, 0), Dd - 1);
            const int iy0c = min(max(iy, 0), Hh - 1);
            const int iy1c = min(max(iy + 1, 0), Hh - 1);
            const int ixl  = min(max(ix, 0), Ww - 2);

            const f2 q00 = load2(V + (size_t)iz0c * PLANE + iy0c * Ww + ixl);
            const f2 q01 = load2(V + (size_t)iz0c * PLANE + iy1c * Ww + ixl);
            const f2 q10 = load2(V + (size_t)iz1c * PLANE + iy0c * Ww + ixl);
            const f2 q11 = load2(V + (size_t)iz1c * PLANE + iy1c * Ww + ixl);

            const float v00 = fmaf(WL, q00.x, WH * q00.y);
            const float v01 = fmaf(WL, q01.x, WH * q01.y);
            const float v10 = fmaf(WL, q10.x, WH * q10.y);
            const float v11 = fmaf(WL, q11.x, WH * q11.y);

            const float vz0 = fmaf(wy0, v00, wy1 * v01);
            const float vz1 = fmaf(wy0, v10, wy1 * v11);
            const float val = fmaf(wz0, vz0, wz1 * vz1);

            __builtin_nontemporal_store(val, obase + (size_t)j * PLANE);
            sum += val;
        }
    }

    // deterministic fixed-point accumulation of x_2d (int add is associative)
    const int pix = (b * Hh + (h0 + h_in)) * Ww + (w0 + w_in);
    atomicAdd(acc + pix, (int)rintf(sum * FPSCALE));
}

// ---------------- Kernel C: convert acc -> x_2d, copy y (float4) ----------
__global__ __launch_bounds__(256) void reduce_kernel(const int* __restrict__ acc,
                                                     const float* __restrict__ yin,
                                                     float* __restrict__ out) {
    const int q = blockIdx.x * 256 + threadIdx.x;   // quad index
    if (q >= N2D / 4) return;
    const int idx = q * 4;
    const int4 a = *(const int4*)(acc + idx);
    float4 s;
    s.x = (float)a.x * INV_FPD;
    s.y = (float)a.y * INV_FPD;
    s.z = (float)a.z * INV_FPD;
    s.w = (float)a.w * INV_FPD;
    *(float4*)(out + idx) = s;
    *(float4*)(out + Y_OFF + idx) = *(const float4*)(yin + idx);
}

extern "C" void kernel_launch(void* const* d_in, const int* in_sizes, int n_in,
                              void* d_out, int out_size, void* d_ws, size_t ws_size,
                              hipStream_t stream) {
    const float* x    = (const float*)d_in[0];
    const float* yin  = (const float*)d_in[1];
    const float* rot0 = (const float*)d_in[2];
    const float* rot1 = (const float*)d_in[3];
    const float* rot2 = (const float*)d_in[4];
    const float* tr1  = (const float*)d_in[5];
    const float* tr2  = (const float*)d_in[6];
    const float* cp   = (const float*)d_in[7];

    float* tbl = (float*)d_ws;                       // NBLK*16 floats = 295 KB
    int*   acc = (int*)(tbl + (size_t)NBLK * 16);    // N2D ints = 590 KB
    (void)ws_size;                                   // ws is amply sized

    tbl_kernel<<<(NBLK + 255) / 256, 256, 0, stream>>>(rot0, rot1, rot2, tr1, tr2, cp, tbl, acc);
    warp_tiled<<<NBLK, 512, 0, stream>>>(x, tbl, (float*)d_out, acc);
    reduce_kernel<<<(N2D / 4 + 255) / 256, 256, 0, stream>>>(acc, yin, (float*)d_out);
}